// Round 16
// baseline (291.519 us; speedup 1.0000x reference)
//
#include <hip/hip_runtime.h>
#include <hip/hip_bf16.h>
#include <hip/hip_fp16.h>

// MHAHead B=8,S=2048,E=512. R20: R15 EXACT + appended ablation dispatches.
//   R19 post-mortem: counted-vmcnt regressed (141 vs 124) -- EIGHTH gemmS
//   structure in the 124-145us band. Bottom-up model says ~40us; counters all
//   <25%. Hypothesis-first editing is exhausted; this round MEASURES.
//   Real path = R15 verbatim (197.4us best). After gemmO: two scratch-writing
//   ablations at z=8 (distinct kernel names in the dispatch table):
//     gemmS_nomask: prologue deleted, unconditional exp  -> gemm+store time
//     gemmS_nogemm: gemm deleted (LDS kept via asm), mask+store kept
//   Decomposition: mask = ref-nomask; gemm = ref-nogemm;
//                  store+residual = nomask+nogemm-ref.
//   dur_us inflates (~+200us of diagnostics); correctness unchanged.

typedef unsigned short u16;
typedef unsigned long long u64;
typedef __attribute__((ext_vector_type(8))) short short8;
typedef __attribute__((ext_vector_type(8))) _Float16 half8;
typedef __attribute__((ext_vector_type(4))) float float4v;

#define S_DIM 2048
#define E_DIM 512
#define NROWS (8 * S_DIM)
#define SCALE 0.044194173824159216f

__device__ __forceinline__ float4v mfma16(short8 a, short8 b, float4v c) {
    return __builtin_amdgcn_mfma_f32_16x16x32_f16(
        __builtin_bit_cast(half8, a), __builtin_bit_cast(half8, b), c, 0, 0, 0);
}
__device__ __forceinline__ float bf2f(unsigned int u) {
    union { unsigned int i; float f; } v; v.i = u << 16; return v.f;
}
__device__ __forceinline__ u16 f2h_bits(float f) {
    union { _Float16 h; u16 u; } v; v.h = (_Float16)f; return v.u;
}
__device__ __forceinline__ float h2f(u16 u) {
    union { u16 u; _Float16 h; } v; v.u = u; return (float)v.h;
}
// tiled u16 index for element (row, col) in a [rows][K] matrix with NT=K/32 tiles
__device__ __forceinline__ size_t tidx(int row, int col, int NT) {
    const int rr = row & 127;
    const int g = 4 * rr + (((col & 31) >> 3) ^ ((rr >> 1) & 3));
    return ((size_t)((row >> 7) * NT + (col >> 5)) * 512 + g) * 8 + (col & 7);
}
__device__ __forceinline__ int detect_bf16(const void* wp) {
    const u16* w = (const u16*)wp;
    int cnt = 0;
    for (int i = 0; i < 64; ++i) {
        int e = (w[2 * i] >> 7) & 0xff;
        cnt += (e >= 100 && e <= 131) ? 1 : 0;
    }
    return cnt >= 40;
}
__device__ __forceinline__ void load8(const void* base, size_t idx, int isbf, float* f) {
    if (isbf) {
        uint4 v = *(const uint4*)((const u16*)base + idx);
        f[0] = bf2f(v.x & 0xffffu); f[1] = bf2f(v.x >> 16);
        f[2] = bf2f(v.y & 0xffffu); f[3] = bf2f(v.y >> 16);
        f[4] = bf2f(v.z & 0xffffu); f[5] = bf2f(v.z >> 16);
        f[6] = bf2f(v.w & 0xffffu); f[7] = bf2f(v.w >> 16);
    } else {
        const float* p = (const float*)base + idx;
        float4 a = *(const float4*)p;
        float4 b = *(const float4*)(p + 4);
        f[0] = a.x; f[1] = a.y; f[2] = a.z; f[3] = a.w;
        f[4] = b.x; f[5] = b.y; f[6] = b.z; f[7] = b.w;
    }
}
__device__ __forceinline__ float load1(const void* base, size_t idx, int isbf) {
    return isbf ? bf2f(((const u16*)base)[idx]) : ((const float*)base)[idx];
}

// async 16B global -> LDS (per-lane src, wave-uniform LDS base + lane*16)
__device__ __forceinline__ void gld16(const u16* g, u16* l) {
    __builtin_amdgcn_global_load_lds(
        (const __attribute__((address_space(1))) void*)g,
        (__attribute__((address_space(3))) void*)l, 16, 0, 0);
}

// row-major staging fallback (fp32/bf16 x input): reg-staged convert
template<int C>
__device__ __forceinline__ void stage(const void* g, size_t off, u16* lds) {
    if constexpr (C == 1) {
        const float* p = (const float*)g + off;
        float4 a = *(const float4*)p;
        float4 b = *(const float4*)(p + 4);
        union { u16 h[8]; short8 v; } pk;
        pk.h[0] = f2h_bits(a.x); pk.h[1] = f2h_bits(a.y);
        pk.h[2] = f2h_bits(a.z); pk.h[3] = f2h_bits(a.w);
        pk.h[4] = f2h_bits(b.x); pk.h[5] = f2h_bits(b.y);
        pk.h[6] = f2h_bits(b.z); pk.h[7] = f2h_bits(b.w);
        *(short8*)lds = pk.v;
    } else {
        uint4 v = *(const uint4*)((const u16*)g + off);
        unsigned int uu[4] = {v.x, v.y, v.z, v.w};
        union { u16 h[8]; short8 v8; } pk;
#pragma unroll
        for (int j = 0; j < 4; ++j) {
            pk.h[2 * j]     = f2h_bits(bf2f(uu[j] & 0xffffu));
            pk.h[2 * j + 1] = f2h_bits(bf2f(uu[j] >> 16));
        }
        *(short8*)lds = pk.v8;
    }
}

// ---------------- conversion kernels (read inputs, write ws tiled) ----------
__global__ __launch_bounds__(256) void conv_w(
    const void* w0, const void* w1, const void* w2,
    const void* b0, const void* b1, const void* b2, u16* wb)
{
    const int z = blockIdx.y;
    const void* w = (z == 0) ? w0 : (z == 1) ? w1 : w2;
    const void* bb = (z == 0) ? b0 : (z == 1) ? b1 : b2;
    const int isbf = detect_bf16(w0);
    const size_t idx = ((size_t)blockIdx.x * 256 + threadIdx.x) * 8;
    const int n = (int)(idx >> 9), kk = (int)(idx & 511);
    float f[8];
    load8(w, idx, isbf, f);
    union { u16 h[8]; uint4 v; } pk;
#pragma unroll
    for (int j = 0; j < 8; ++j) pk.h[j] = f2h_bits(f[j]);
    *(uint4*)(wb + (size_t)z * 262144 + tidx(n, kk, 16)) = pk.v;
    if (blockIdx.x == 0) {
        u16* bbase = wb + 3 * 262144 + z * 512;
#pragma unroll
        for (int j = 0; j < 2; ++j) {
            int i = threadIdx.x * 2 + j;
            bbase[i] = f2h_bits(load1(bb, i, isbf));
        }
    }
}

// x fp32/bf16 -> f16 TILED [RB 128][16 tiles][512 granules] in ws.
__global__ __launch_bounds__(256) void conv_x(
    const void* x, const void* wq_orig, u16* xh)
{
    const int w = threadIdx.x >> 6, l = threadIdx.x & 63;
    const int row = blockIdx.x * 4 + w;
    union { u16 h[8]; uint4 v; } pk;
    if (detect_bf16(wq_orig)) {
        uint4 v = *(const uint4*)((const u16*)x + (size_t)row * 512 + l * 8);
        unsigned int uu[4] = {v.x, v.y, v.z, v.w};
#pragma unroll
        for (int j = 0; j < 4; ++j) {
            pk.h[2 * j]     = f2h_bits(bf2f(uu[j] & 0xffffu));
            pk.h[2 * j + 1] = f2h_bits(bf2f(uu[j] >> 16));
        }
    } else {
        const float* src = (const float*)x + (size_t)row * 512 + l * 8;
        float4 a = *(const float4*)src;
        float4 b = *(const float4*)(src + 4);
        pk.h[0] = f2h_bits(a.x); pk.h[1] = f2h_bits(a.y);
        pk.h[2] = f2h_bits(a.z); pk.h[3] = f2h_bits(a.w);
        pk.h[4] = f2h_bits(b.x); pk.h[5] = f2h_bits(b.y);
        pk.h[6] = f2h_bits(b.z); pk.h[7] = f2h_bits(b.w);
    }
    *(uint4*)(xh + tidx(row, l * 8, 16)) = pk.v;
}

// ---------------- shared GEMM core (R15: BK=32, 4 waves, tiled gld16) -------
template<int ONES, int CA, int CB>
__device__ __forceinline__ void gemm_core(
    const void* __restrict__ A, int sA, const void* __restrict__ B, int sB, int K,
    u16* As, u16* Bs, float4v acc[4][4], float4v accS[4])
{
    const int t = threadIdx.x;
    const int w = t >> 6, l = t & 63;
    const int lane15 = l & 15, quad = l >> 4;
    const int wm = w & 1, wn = w >> 1;

    short8 ones;
#pragma unroll
    for (int j = 0; j < 8; ++j) ones[j] = (short)0x3C00;   // f16 1.0

    for (int kt = 0; kt < K; kt += 32) {
        const int kti = kt >> 5;
        __syncthreads();
#pragma unroll
        for (int i = 0; i < 2; ++i) {
            const int fg = w * 128 + i * 64 + l;
            const int r = fg >> 2;
            const int kq = (fg & 3) ^ ((r >> 1) & 3);
            if constexpr (CA == 0)
                gld16((const u16*)A + (size_t)kti * 4096 + fg * 8, As + fg * 8);
            else
                stage<CA>(A, (size_t)r * sA + kt + kq * 8, As + fg * 8);
            if constexpr (CB == 0)
                gld16((const u16*)B + (size_t)kti * 4096 + fg * 8, Bs + fg * 8);
            else
                stage<CB>(B, (size_t)r * sB + kt + kq * 8, Bs + fg * 8);
        }
        __syncthreads();

        short8 af[4], bf[4];
#pragma unroll
        for (int mi = 0; mi < 4; ++mi) {
            const int r = wm * 64 + mi * 16 + lane15;
            af[mi] = *(const short8*)&As[(4 * r + (quad ^ ((r >> 1) & 3))) * 8];
        }
#pragma unroll
        for (int ni = 0; ni < 4; ++ni) {
            const int r = wn * 64 + ni * 16 + lane15;
            bf[ni] = *(const short8*)&Bs[(4 * r + (quad ^ ((r >> 1) & 3))) * 8];
        }
#pragma unroll
        for (int mi = 0; mi < 4; ++mi) {
#pragma unroll
            for (int ni = 0; ni < 4; ++ni)
                acc[mi][ni] = mfma16(af[mi], bf[ni], acc[mi][ni]);
            if (ONES) accS[mi] = mfma16(af[mi], ones, accS[mi]);
        }
    }
}

#define GEMM_PRE()                                                     \
    __shared__ u16 As[4096] __attribute__((aligned(16)));              \
    __shared__ u16 Bs[4096] __attribute__((aligned(16)));              \
    const int t = threadIdx.x;                                         \
    const int w = t >> 6, l = t & 63;                                  \
    const int lane15 = l & 15, quad = l >> 4;                          \
    const int wm = w & 1, wn = w >> 1;                                 \
    (void)l; (void)w;                                                  \
    float4v acc[4][4];                                                 \
    float4v accS[4];                                                   \
    _Pragma("unroll") for (int mi = 0; mi < 4; ++mi) {                 \
        accS[mi] = (float4v){0.f, 0.f, 0.f, 0.f};                      \
        _Pragma("unroll") for (int ni = 0; ni < 4; ++ni)               \
            acc[mi][ni] = (float4v){0.f, 0.f, 0.f, 0.f};               \
    }

// ---------------- proj: Q, K, Vt (outputs tiled; R15 verbatim) --------------
template<int XM>
__global__ __launch_bounds__(256) void proj_gemm(
    const void* __restrict__ xsrc, const u16* __restrict__ wb,
    u16* __restrict__ qb, u16* __restrict__ kb, u16* __restrict__ vt)
{
    GEMM_PRE();
    const int z = blockIdx.z;
    const int hh = blockIdx.y * 4 + blockIdx.x;
    const int sl = (hh & 7) * 64 + (hh >> 3);
    const int ty = sl >> 2, tx = sl & 3;
    const u16* bias = wb + 3 * 262144 + z * 512;

    int m0, n0;
    if (z < 2) { m0 = ty * 128; n0 = tx * 128; }
    else       { m0 = tx * 128; n0 = ty * 128; }

    if (z < 2) {
        const void* B = wb + (size_t)z * 262144 + (size_t)(n0 >> 7) * 16 * 4096;
        if (XM == 0) {
            const void* A = (const u16*)xsrc + (size_t)(m0 >> 7) * 16 * 4096;
            gemm_core<0, 0, 0>(A, 512, B, 512, 512, As, Bs, acc, accS);
        } else if (XM == 1) {
            const void* A = (const float*)xsrc + (size_t)m0 * 512;
            gemm_core<0, 1, 0>(A, 512, B, 512, 512, As, Bs, acc, accS);
        } else {
            const void* A = (const u16*)xsrc + (size_t)m0 * 512;
            gemm_core<0, 2, 0>(A, 512, B, 512, 512, As, Bs, acc, accS);
        }
    } else {
        const void* A = wb + (size_t)2 * 262144 + (size_t)(m0 >> 7) * 16 * 4096;
        if (XM == 0) {
            const void* B = (const u16*)xsrc + (size_t)(n0 >> 7) * 16 * 4096;
            gemm_core<0, 0, 0>(A, 512, B, 512, 512, As, Bs, acc, accS);
        } else if (XM == 1) {
            const void* B = (const float*)xsrc + (size_t)n0 * 512;
            gemm_core<0, 0, 1>(A, 512, B, 512, 512, As, Bs, acc, accS);
        } else {
            const void* B = (const u16*)xsrc + (size_t)n0 * 512;
            gemm_core<0, 0, 2>(A, 512, B, 512, 512, As, Bs, acc, accS);
        }
    }

    if (z < 2) {
        u16* dst = z ? kb : qb;                 // tiled [rows/128][16][512]g
        float bcol[4];
#pragma unroll
        for (int ni = 0; ni < 4; ++ni)
            bcol[ni] = h2f(bias[n0 + wn * 64 + ni * 16 + lane15]);
#pragma unroll
        for (int mi = 0; mi < 4; ++mi)
#pragma unroll
            for (int ni = 0; ni < 4; ++ni)
#pragma unroll
                for (int r = 0; r < 4; ++r) {
                    const int row = m0 + wm * 64 + mi * 16 + quad * 4 + r;
                    const int col = n0 + wn * 64 + ni * 16 + lane15;
                    dst[tidx(row, col, 16)] = f2h_bits(acc[mi][ni][r] + bcol[ni]);
                }
    } else {
        // Vt tiled per batch: [b][4 RBe][64 T][512]g ; rows = e, K = token
#pragma unroll
        for (int mi = 0; mi < 4; ++mi)
#pragma unroll
            for (int r = 0; r < 4; ++r) {
                const int e = m0 + wm * 64 + mi * 16 + quad * 4 + r;      // 0..511
                const float bias_e = h2f(bias[e]);
#pragma unroll
                for (int ni = 0; ni < 4; ++ni) {
                    const int tok = n0 + wn * 64 + ni * 16 + lane15;
                    const int b = tok >> 11, kk = tok & 2047;
                    vt[(size_t)b * 1048576 + tidx(e, kk, 64)] =
                        f2h_bits(acc[mi][ni][r] + bias_e);
                }
            }
    }
}

// ---------------- gemmS: R15 verbatim (ref) ----------------
__global__ __launch_bounds__(256) void gemmS(
    const u16* __restrict__ qb, const u16* __restrict__ kb,
    const int* __restrict__ mask, u16* __restrict__ Sdst, int b0)
{
    GEMM_PRE();
    __shared__ u64 maskw[256];          // [wave][row_local]
    const int zb = blockIdx.z;
    const int b = b0 + zb;
    const int hh = blockIdx.y * 16 + blockIdx.x;
    const int sl = (hh & 7) * 32 + (hh >> 3);
    const int m0 = (sl >> 4) * 128, n0 = (sl & 15) * 128;

    {   // mask pack
        const int* mrow = mask + ((size_t)b * S_DIM + m0 + wm * 64) * S_DIM
                               + n0 + wn * 64 + l;
#pragma unroll
        for (int rnd = 0; rnd < 4; ++rnd) {
            int v[16];
#pragma unroll
            for (int i = 0; i < 16; ++i)
                v[i] = mrow[(size_t)(rnd * 16 + i) * S_DIM];
            u64 bb[16];
#pragma unroll
            for (int i = 0; i < 16; ++i)
                bb[i] = __ballot(v[i] > 0);
            if (l == 0) {
#pragma unroll
                for (int i = 0; i < 16; ++i)
                    maskw[w * 64 + rnd * 16 + i] = bb[i];
            }
        }
    }

    const u16* A = qb + (size_t)((b * S_DIM + m0) >> 7) * 16 * 4096;
    const u16* B = kb + (size_t)((b * S_DIM + n0) >> 7) * 16 * 4096;
    gemm_core<0, 0, 0>(A, 512, B, 512, 512, As, Bs, acc, accS);

    u16* Sb = Sdst + (size_t)zb * 4194304;      // tiled [16 RB][64 T][512]g
#pragma unroll
    for (int mi = 0; mi < 4; ++mi)
#pragma unroll
        for (int r = 0; r < 4; ++r) {
            const int row = m0 + wm * 64 + mi * 16 + quad * 4 + r;
            const u64 wbits = maskw[w * 64 + mi * 16 + quad * 4 + r];
            const int col0 = n0 + wn * 64 + lane15;
#pragma unroll
            for (int ni = 0; ni < 4; ++ni) {
                const int masked = (int)((wbits >> (lane15 + ni * 16)) & 1);
                const float p = masked ? 0.f : __expf(acc[mi][ni][r] * SCALE);
                Sb[tidx(row, col0 + ni * 16, 64)] = f2h_bits(p);
            }
        }
}

// ---------------- ABLATION: gemmS without mask path (scratch output) --------
__global__ __launch_bounds__(256) void gemmS_nomask(
    const u16* __restrict__ qb, const u16* __restrict__ kb,
    u16* __restrict__ Sdst, int b0)
{
    GEMM_PRE();
    const int zb = blockIdx.z;
    const int b = b0 + zb;
    const int hh = blockIdx.y * 16 + blockIdx.x;
    const int sl = (hh & 7) * 32 + (hh >> 3);
    const int m0 = (sl >> 4) * 128, n0 = (sl & 15) * 128;

    const u16* A = qb + (size_t)((b * S_DIM + m0) >> 7) * 16 * 4096;
    const u16* B = kb + (size_t)((b * S_DIM + n0) >> 7) * 16 * 4096;
    gemm_core<0, 0, 0>(A, 512, B, 512, 512, As, Bs, acc, accS);

    u16* Sb = Sdst + (size_t)zb * 4194304;
#pragma unroll
    for (int mi = 0; mi < 4; ++mi)
#pragma unroll
        for (int r = 0; r < 4; ++r) {
            const int row = m0 + wm * 64 + mi * 16 + quad * 4 + r;
            const int col0 = n0 + wn * 64 + lane15;
#pragma unroll
            for (int ni = 0; ni < 4; ++ni) {
                const float p = __expf(acc[mi][ni][r] * SCALE);
                Sb[tidx(row, col0 + ni * 16, 64)] = f2h_bits(p);
            }
        }
}

// ---------------- ABLATION: gemmS without gemm loop (scratch output) --------
__global__ __launch_bounds__(256) void gemmS_nogemm(
    const int* __restrict__ mask, u16* __restrict__ Sdst, int b0)
{
    __shared__ u16 As[4096] __attribute__((aligned(16)));
    __shared__ u16 Bs[4096] __attribute__((aligned(16)));
    __shared__ u64 maskw[256];
    const int t = threadIdx.x;
    const int w = t >> 6, l = t & 63;
    const int lane15 = l & 15, quad = l >> 4;
    const int wm = w & 1, wn = w >> 1;
    const int zb = blockIdx.z;
    const int b = b0 + zb;
    const int hh = blockIdx.y * 16 + blockIdx.x;
    const int sl = (hh & 7) * 32 + (hh >> 3);
    const int m0 = (sl >> 4) * 128, n0 = (sl & 15) * 128;

    // keep LDS allocated so occupancy matches ref as closely as possible
    As[t] = (u16)t; Bs[t] = (u16)t;
    __syncthreads();
    asm volatile("" :: "v"((int)As[(t + 7) & 4095]), "v"((int)Bs[(t + 11) & 4095]));

    {   // mask pack (identical to ref)
        const int* mrow = mask + ((size_t)b * S_DIM + m0 + wm * 64) * S_DIM
                               + n0 + wn * 64 + l;
#pragma unroll
        for (int rnd = 0; rnd < 4; ++rnd) {
            int v[16];
#pragma unroll
            for (int i = 0; i < 16; ++i)
                v[i] = mrow[(size_t)(rnd * 16 + i) * S_DIM];
            u64 bb[16];
#pragma unroll
            for (int i = 0; i < 16; ++i)
                bb[i] = __ballot(v[i] > 0);
            if (l == 0) {
#pragma unroll
                for (int i = 0; i < 16; ++i)
                    maskw[w * 64 + rnd * 16 + i] = bb[i];
            }
        }
    }
    __syncthreads();

    u16* Sb = Sdst + (size_t)zb * 4194304;
#pragma unroll
    for (int mi = 0; mi < 4; ++mi)
#pragma unroll
        for (int r = 0; r < 4; ++r) {
            const int row = m0 + wm * 64 + mi * 16 + quad * 4 + r;
            const u64 wbits = maskw[w * 64 + mi * 16 + quad * 4 + r];
            const int col0 = n0 + wn * 64 + lane15;
#pragma unroll
            for (int ni = 0; ni < 4; ++ni) {
                const int masked = (int)((wbits >> (lane15 + ni * 16)) & 1);
                const float p = masked ? 0.f : 1.0f;
                Sb[tidx(row, col0 + ni * 16, 64)] = f2h_bits(p);
            }
        }
}

// ---------------- gemmO: R15 verbatim ----------------
__global__ __launch_bounds__(256) void gemmO(
    const u16* __restrict__ Ssrc, const u16* __restrict__ vt,
    float* __restrict__ outp, int b0)
{
    GEMM_PRE();
    const int zb = blockIdx.z;
    const int b = b0 + zb;
    const int hh = blockIdx.y * 4 + blockIdx.x;
    const int sl = (hh & 7) * 8 + (hh >> 3);
    const int m0 = (sl >> 2) * 128, n0 = (sl & 3) * 128;
    const u16* A = Ssrc + (size_t)zb * 4194304 + (size_t)(m0 >> 7) * 64 * 4096;
    const u16* B = vt + (size_t)b * 1048576 + (size_t)(n0 >> 7) * 64 * 4096;

    gemm_core<1, 0, 0>(A, S_DIM, B, S_DIM, S_DIM, As, Bs, acc, accS);

#pragma unroll
    for (int mi = 0; mi < 4; ++mi)
#pragma unroll
        for (int r = 0; r < 4; ++r) {
            const int row = m0 + wm * 64 + mi * 16 + quad * 4 + r;
            const float inv = 1.f / accS[mi][r];
#pragma unroll
            for (int ni = 0; ni < 4; ++ni) {
                const int col = n0 + wn * 64 + ni * 16 + lane15;
                outp[((size_t)b * S_DIM + row) * E_DIM + col] = acc[mi][ni][r] * inv;
            }
        }
}

extern "C" void kernel_launch(void* const* d_in, const int* in_sizes, int n_in,
                              void* d_out, int out_size, void* d_ws, size_t ws_size,
                              hipStream_t stream) {
    const void* x    = d_in[0];
    const int*  mask = (const int*)d_in[1];
    const void* wq   = d_in[2];
    const void* bq   = d_in[3];
    const void* wk   = d_in[4];
    const void* bk   = d_in[5];
    const void* wv   = d_in[6];
    const void* bv   = d_in[7];

    const size_t MB   = 1ull << 20;
    const size_t QSZ  = (size_t)NROWS * E_DIM;          // u16 elems per Q/K/Vt/xh
    const size_t S_PB = (size_t)S_DIM * S_DIM;          // u16 elems per S batch

    u16* wb   = (u16*)d_ws;                             // 2 MB (weights+bias f16)
    u16* qb   = (u16*)((char*)d_ws + 2 * MB);
    u16* kb   = qb + QSZ;
    u16* vtb  = kb + QSZ;
    u16* xh   = vtb + QSZ;                              // 16.8 MB f16 x (dead after proj)
    u16* sS   = xh;                                     // S scratch aliases xh

    const size_t fixed = 2 * MB + 3 * QSZ * 2;          // 52.4 MB (pre-xh)
    const size_t avail = (ws_size > fixed) ? (ws_size - fixed) : 0;
    const int use_xh = avail >= (QSZ * 2 + 2 * S_PB);   // xh + >=2 S batches
    const size_t availB = avail / (S_PB * 2);
    const int P = (availB >= 8) ? 8 : (availB >= 4) ? 4 : (availB >= 2) ? 2 : 1;

    conv_w<<<dim3(128, 3), 256, 0, stream>>>(wq, wk, wv, bq, bk, bv, wb);

    if (use_xh) {
        conv_x<<<NROWS / 4, 256, 0, stream>>>(x, wq, xh);
        proj_gemm<0><<<dim3(4, 128, 3), 256, 0, stream>>>(xh, wb, qb, kb, vtb);
    } else {
        if (in_sizes[0] >= (int)(NROWS * 512 * 4))
            proj_gemm<1><<<dim3(4, 128, 3), 256, 0, stream>>>(x, wb, qb, kb, vtb);
        else
            proj_gemm<2><<<dim3(4, 128, 3), 256, 0, stream>>>(x, wb, qb, kb, vtb);
    }

    for (int p = 0; p < 8; p += P) {
        gemmS<<<dim3(16, 16, P), 256, 0, stream>>>(qb, kb, mask, sS, p);
        gemmO<<<dim3(4, 16, P), 256, 0, stream>>>(sS, vtb, (float*)d_out, p);
    }

    // ---- diagnostics (after real output is complete; write dead sS) ----
    if (P == 8) {
        gemmS_nogemm<<<dim3(16, 16, 8), 256, 0, stream>>>(mask, sS, 0);
        gemmS_nomask<<<dim3(16, 16, 8), 256, 0, stream>>>(qb, kb, sS, 0);
    }
}

// Round 17
// 206.018 us; speedup vs baseline: 1.4150x; 1.4150x over previous
//
#include <hip/hip_runtime.h>
#include <hip/hip_bf16.h>
#include <hip/hip_fp16.h>

// MHAHead B=8,S=2048,E=512. R21: R15 + separated mask stream (bitmask pass).
//   R20 ablation: ref gemmS 125.5us but nogemm+nomask sum to only ~94us ->
//   store term NEGATIVE under additive model -> >=31us SUPERADDITIVE
//   interference between the in-kernel 134MB mask read and the gemm path.
//   Eight schedule variants (R12-R19) never moved gemmS because the coupling,
//   not the schedule, was the cost. Fix = R8's separation, now with R15's
//   fast proj: conv_mask packs mask->4MB bitmask (ballot, ~22us ~= HBM floor);
//   gemmS epilogue reads 16 broadcast u64/thread from L2-resident bitmask.
//   All GEMM kernels/layouts = R15 verbatim.

typedef unsigned short u16;
typedef unsigned long long u64;
typedef __attribute__((ext_vector_type(8))) short short8;
typedef __attribute__((ext_vector_type(8))) _Float16 half8;
typedef __attribute__((ext_vector_type(4))) float float4v;

#define S_DIM 2048
#define E_DIM 512
#define NROWS (8 * S_DIM)
#define SCALE 0.044194173824159216f
#define NWORDS ((size_t)8 * S_DIM * S_DIM / 64)   // 524288 u64 words (4 MB)

__device__ __forceinline__ float4v mfma16(short8 a, short8 b, float4v c) {
    return __builtin_amdgcn_mfma_f32_16x16x32_f16(
        __builtin_bit_cast(half8, a), __builtin_bit_cast(half8, b), c, 0, 0, 0);
}
__device__ __forceinline__ float bf2f(unsigned int u) {
    union { unsigned int i; float f; } v; v.i = u << 16; return v.f;
}
__device__ __forceinline__ u16 f2h_bits(float f) {
    union { _Float16 h; u16 u; } v; v.h = (_Float16)f; return v.u;
}
__device__ __forceinline__ float h2f(u16 u) {
    union { u16 u; _Float16 h; } v; v.u = u; return (float)v.h;
}
// tiled u16 index for element (row, col) in a [rows][K] matrix with NT=K/32 tiles
__device__ __forceinline__ size_t tidx(int row, int col, int NT) {
    const int rr = row & 127;
    const int g = 4 * rr + (((col & 31) >> 3) ^ ((rr >> 1) & 3));
    return ((size_t)((row >> 7) * NT + (col >> 5)) * 512 + g) * 8 + (col & 7);
}
__device__ __forceinline__ int detect_bf16(const void* wp) {
    const u16* w = (const u16*)wp;
    int cnt = 0;
    for (int i = 0; i < 64; ++i) {
        int e = (w[2 * i] >> 7) & 0xff;
        cnt += (e >= 100 && e <= 131) ? 1 : 0;
    }
    return cnt >= 40;
}
__device__ __forceinline__ void load8(const void* base, size_t idx, int isbf, float* f) {
    if (isbf) {
        uint4 v = *(const uint4*)((const u16*)base + idx);
        f[0] = bf2f(v.x & 0xffffu); f[1] = bf2f(v.x >> 16);
        f[2] = bf2f(v.y & 0xffffu); f[3] = bf2f(v.y >> 16);
        f[4] = bf2f(v.z & 0xffffu); f[5] = bf2f(v.z >> 16);
        f[6] = bf2f(v.w & 0xffffu); f[7] = bf2f(v.w >> 16);
    } else {
        const float* p = (const float*)base + idx;
        float4 a = *(const float4*)p;
        float4 b = *(const float4*)(p + 4);
        f[0] = a.x; f[1] = a.y; f[2] = a.z; f[3] = a.w;
        f[4] = b.x; f[5] = b.y; f[6] = b.z; f[7] = b.w;
    }
}
__device__ __forceinline__ float load1(const void* base, size_t idx, int isbf) {
    return isbf ? bf2f(((const u16*)base)[idx]) : ((const float*)base)[idx];
}

// async 16B global -> LDS (per-lane src, wave-uniform LDS base + lane*16)
__device__ __forceinline__ void gld16(const u16* g, u16* l) {
    __builtin_amdgcn_global_load_lds(
        (const __attribute__((address_space(1))) void*)g,
        (__attribute__((address_space(3))) void*)l, 16, 0, 0);
}

// row-major staging fallback (fp32/bf16 x input): reg-staged convert
template<int C>
__device__ __forceinline__ void stage(const void* g, size_t off, u16* lds) {
    if constexpr (C == 1) {
        const float* p = (const float*)g + off;
        float4 a = *(const float4*)p;
        float4 b = *(const float4*)(p + 4);
        union { u16 h[8]; short8 v; } pk;
        pk.h[0] = f2h_bits(a.x); pk.h[1] = f2h_bits(a.y);
        pk.h[2] = f2h_bits(a.z); pk.h[3] = f2h_bits(a.w);
        pk.h[4] = f2h_bits(b.x); pk.h[5] = f2h_bits(b.y);
        pk.h[6] = f2h_bits(b.z); pk.h[7] = f2h_bits(b.w);
        *(short8*)lds = pk.v;
    } else {
        uint4 v = *(const uint4*)((const u16*)g + off);
        unsigned int uu[4] = {v.x, v.y, v.z, v.w};
        union { u16 h[8]; short8 v8; } pk;
#pragma unroll
        for (int j = 0; j < 4; ++j) {
            pk.h[2 * j]     = f2h_bits(bf2f(uu[j] & 0xffffu));
            pk.h[2 * j + 1] = f2h_bits(bf2f(uu[j] >> 16));
        }
        *(short8*)lds = pk.v8;
    }
}

// ---------------- conversion kernels (read inputs, write ws) ----------------
__global__ __launch_bounds__(256) void conv_w(
    const void* w0, const void* w1, const void* w2,
    const void* b0, const void* b1, const void* b2, u16* wb)
{
    const int z = blockIdx.y;
    const void* w = (z == 0) ? w0 : (z == 1) ? w1 : w2;
    const void* bb = (z == 0) ? b0 : (z == 1) ? b1 : b2;
    const int isbf = detect_bf16(w0);
    const size_t idx = ((size_t)blockIdx.x * 256 + threadIdx.x) * 8;
    const int n = (int)(idx >> 9), kk = (int)(idx & 511);
    float f[8];
    load8(w, idx, isbf, f);
    union { u16 h[8]; uint4 v; } pk;
#pragma unroll
    for (int j = 0; j < 8; ++j) pk.h[j] = f2h_bits(f[j]);
    *(uint4*)(wb + (size_t)z * 262144 + tidx(n, kk, 16)) = pk.v;
    if (blockIdx.x == 0) {
        u16* bbase = wb + 3 * 262144 + z * 512;
#pragma unroll
        for (int j = 0; j < 2; ++j) {
            int i = threadIdx.x * 2 + j;
            bbase[i] = f2h_bits(load1(bb, i, isbf));
        }
    }
}

// mask int32 -> bit-packed u64 (bit l of word w = mask[w*64+l] > 0). BW-bound.
__global__ __launch_bounds__(256) void conv_mask(
    const int* __restrict__ mask, u64* __restrict__ mbits)
{
    const int gw = blockIdx.x * 4 + (threadIdx.x >> 6);   // global wave id
    const int l = threadIdx.x & 63;
    const size_t w0 = (size_t)gw * 64;
#pragma unroll 1
    for (int i = 0; i < 64; i += 4) {
        const int m0 = mask[(w0 + i + 0) * 64 + l];
        const int m1 = mask[(w0 + i + 1) * 64 + l];
        const int m2 = mask[(w0 + i + 2) * 64 + l];
        const int m3 = mask[(w0 + i + 3) * 64 + l];
        const u64 b0 = __ballot(m0 > 0);
        const u64 b1 = __ballot(m1 > 0);
        const u64 b2 = __ballot(m2 > 0);
        const u64 b3 = __ballot(m3 > 0);
        if (l == 0) {
            mbits[w0 + i + 0] = b0; mbits[w0 + i + 1] = b1;
            mbits[w0 + i + 2] = b2; mbits[w0 + i + 3] = b3;
        }
    }
}

// x fp32/bf16 -> f16 TILED [RB 128][16 tiles][512 granules] in ws.
__global__ __launch_bounds__(256) void conv_x(
    const void* x, const void* wq_orig, u16* xh)
{
    const int w = threadIdx.x >> 6, l = threadIdx.x & 63;
    const int row = blockIdx.x * 4 + w;
    union { u16 h[8]; uint4 v; } pk;
    if (detect_bf16(wq_orig)) {
        uint4 v = *(const uint4*)((const u16*)x + (size_t)row * 512 + l * 8);
        unsigned int uu[4] = {v.x, v.y, v.z, v.w};
#pragma unroll
        for (int j = 0; j < 4; ++j) {
            pk.h[2 * j]     = f2h_bits(bf2f(uu[j] & 0xffffu));
            pk.h[2 * j + 1] = f2h_bits(bf2f(uu[j] >> 16));
        }
    } else {
        const float* src = (const float*)x + (size_t)row * 512 + l * 8;
        float4 a = *(const float4*)src;
        float4 b = *(const float4*)(src + 4);
        pk.h[0] = f2h_bits(a.x); pk.h[1] = f2h_bits(a.y);
        pk.h[2] = f2h_bits(a.z); pk.h[3] = f2h_bits(a.w);
        pk.h[4] = f2h_bits(b.x); pk.h[5] = f2h_bits(b.y);
        pk.h[6] = f2h_bits(b.z); pk.h[7] = f2h_bits(b.w);
    }
    *(uint4*)(xh + tidx(row, l * 8, 16)) = pk.v;
}

// ---------------- shared GEMM core (R15: BK=32, 4 waves, tiled gld16) -------
template<int ONES, int CA, int CB>
__device__ __forceinline__ void gemm_core(
    const void* __restrict__ A, int sA, const void* __restrict__ B, int sB, int K,
    u16* As, u16* Bs, float4v acc[4][4], float4v accS[4])
{
    const int t = threadIdx.x;
    const int w = t >> 6, l = t & 63;
    const int lane15 = l & 15, quad = l >> 4;
    const int wm = w & 1, wn = w >> 1;

    short8 ones;
#pragma unroll
    for (int j = 0; j < 8; ++j) ones[j] = (short)0x3C00;   // f16 1.0

    for (int kt = 0; kt < K; kt += 32) {
        const int kti = kt >> 5;
        __syncthreads();
#pragma unroll
        for (int i = 0; i < 2; ++i) {
            const int fg = w * 128 + i * 64 + l;
            const int r = fg >> 2;
            const int kq = (fg & 3) ^ ((r >> 1) & 3);
            if constexpr (CA == 0)
                gld16((const u16*)A + (size_t)kti * 4096 + fg * 8, As + fg * 8);
            else
                stage<CA>(A, (size_t)r * sA + kt + kq * 8, As + fg * 8);
            if constexpr (CB == 0)
                gld16((const u16*)B + (size_t)kti * 4096 + fg * 8, Bs + fg * 8);
            else
                stage<CB>(B, (size_t)r * sB + kt + kq * 8, Bs + fg * 8);
        }
        __syncthreads();

        short8 af[4], bf[4];
#pragma unroll
        for (int mi = 0; mi < 4; ++mi) {
            const int r = wm * 64 + mi * 16 + lane15;
            af[mi] = *(const short8*)&As[(4 * r + (quad ^ ((r >> 1) & 3))) * 8];
        }
#pragma unroll
        for (int ni = 0; ni < 4; ++ni) {
            const int r = wn * 64 + ni * 16 + lane15;
            bf[ni] = *(const short8*)&Bs[(4 * r + (quad ^ ((r >> 1) & 3))) * 8];
        }
#pragma unroll
        for (int mi = 0; mi < 4; ++mi) {
#pragma unroll
            for (int ni = 0; ni < 4; ++ni)
                acc[mi][ni] = mfma16(af[mi], bf[ni], acc[mi][ni]);
            if (ONES) accS[mi] = mfma16(af[mi], ones, accS[mi]);
        }
    }
}

#define GEMM_PRE()                                                     \
    __shared__ u16 As[4096] __attribute__((aligned(16)));              \
    __shared__ u16 Bs[4096] __attribute__((aligned(16)));              \
    const int t = threadIdx.x;                                         \
    const int w = t >> 6, l = t & 63;                                  \
    const int lane15 = l & 15, quad = l >> 4;                          \
    const int wm = w & 1, wn = w >> 1;                                 \
    (void)l; (void)w;                                                  \
    float4v acc[4][4];                                                 \
    float4v accS[4];                                                   \
    _Pragma("unroll") for (int mi = 0; mi < 4; ++mi) {                 \
        accS[mi] = (float4v){0.f, 0.f, 0.f, 0.f};                      \
        _Pragma("unroll") for (int ni = 0; ni < 4; ++ni)               \
            acc[mi][ni] = (float4v){0.f, 0.f, 0.f, 0.f};               \
    }

// ---------------- proj: Q, K, Vt (outputs tiled; R15 verbatim) --------------
template<int XM>
__global__ __launch_bounds__(256) void proj_gemm(
    const void* __restrict__ xsrc, const u16* __restrict__ wb,
    u16* __restrict__ qb, u16* __restrict__ kb, u16* __restrict__ vt)
{
    GEMM_PRE();
    const int z = blockIdx.z;
    const int hh = blockIdx.y * 4 + blockIdx.x;
    const int sl = (hh & 7) * 64 + (hh >> 3);
    const int ty = sl >> 2, tx = sl & 3;
    const u16* bias = wb + 3 * 262144 + z * 512;

    int m0, n0;
    if (z < 2) { m0 = ty * 128; n0 = tx * 128; }
    else       { m0 = tx * 128; n0 = ty * 128; }

    if (z < 2) {
        const void* B = wb + (size_t)z * 262144 + (size_t)(n0 >> 7) * 16 * 4096;
        if (XM == 0) {
            const void* A = (const u16*)xsrc + (size_t)(m0 >> 7) * 16 * 4096;
            gemm_core<0, 0, 0>(A, 512, B, 512, 512, As, Bs, acc, accS);
        } else if (XM == 1) {
            const void* A = (const float*)xsrc + (size_t)m0 * 512;
            gemm_core<0, 1, 0>(A, 512, B, 512, 512, As, Bs, acc, accS);
        } else {
            const void* A = (const u16*)xsrc + (size_t)m0 * 512;
            gemm_core<0, 2, 0>(A, 512, B, 512, 512, As, Bs, acc, accS);
        }
    } else {
        const void* A = wb + (size_t)2 * 262144 + (size_t)(m0 >> 7) * 16 * 4096;
        if (XM == 0) {
            const void* B = (const u16*)xsrc + (size_t)(n0 >> 7) * 16 * 4096;
            gemm_core<0, 0, 0>(A, 512, B, 512, 512, As, Bs, acc, accS);
        } else if (XM == 1) {
            const void* B = (const float*)xsrc + (size_t)n0 * 512;
            gemm_core<0, 0, 1>(A, 512, B, 512, 512, As, Bs, acc, accS);
        } else {
            const void* B = (const u16*)xsrc + (size_t)n0 * 512;
            gemm_core<0, 0, 2>(A, 512, B, 512, 512, As, Bs, acc, accS);
        }
    }

    if (z < 2) {
        u16* dst = z ? kb : qb;                 // tiled [rows/128][16][512]g
        float bcol[4];
#pragma unroll
        for (int ni = 0; ni < 4; ++ni)
            bcol[ni] = h2f(bias[n0 + wn * 64 + ni * 16 + lane15]);
#pragma unroll
        for (int mi = 0; mi < 4; ++mi)
#pragma unroll
            for (int ni = 0; ni < 4; ++ni)
#pragma unroll
                for (int r = 0; r < 4; ++r) {
                    const int row = m0 + wm * 64 + mi * 16 + quad * 4 + r;
                    const int col = n0 + wn * 64 + ni * 16 + lane15;
                    dst[tidx(row, col, 16)] = f2h_bits(acc[mi][ni][r] + bcol[ni]);
                }
    } else {
        // Vt tiled per batch: [b][4 RBe][64 T][512]g ; rows = e, K = token
#pragma unroll
        for (int mi = 0; mi < 4; ++mi)
#pragma unroll
            for (int r = 0; r < 4; ++r) {
                const int e = m0 + wm * 64 + mi * 16 + quad * 4 + r;      // 0..511
                const float bias_e = h2f(bias[e]);
#pragma unroll
                for (int ni = 0; ni < 4; ++ni) {
                    const int tok = n0 + wn * 64 + ni * 16 + lane15;
                    const int b = tok >> 11, kk = tok & 2047;
                    vt[(size_t)b * 1048576 + tidx(e, kk, 64)] =
                        f2h_bits(acc[mi][ni][r] + bias_e);
                }
            }
    }
}

// ---------------- gemmS: gemm + bitmask epilogue (no mask stream inside) ----
__global__ __launch_bounds__(256) void gemmS(
    const u16* __restrict__ qb, const u16* __restrict__ kb,
    const u64* __restrict__ mbits, u16* __restrict__ Sdst, int b0)
{
    GEMM_PRE();
    const int zb = blockIdx.z;
    const int b = b0 + zb;
    const int hh = blockIdx.y * 16 + blockIdx.x;
    const int sl = (hh & 7) * 32 + (hh >> 3);
    const int m0 = (sl >> 4) * 128, n0 = (sl & 15) * 128;

    const u16* A = qb + (size_t)((b * S_DIM + m0) >> 7) * 16 * 4096;
    const u16* B = kb + (size_t)((b * S_DIM + n0) >> 7) * 16 * 4096;
    gemm_core<0, 0, 0>(A, 512, B, 512, 512, As, Bs, acc, accS);

    // bit word for this wave's 64-col window: cols [n0+wn*64, +64)
    const u64* mb = mbits + (size_t)b * S_DIM * 32 + (n0 >> 6) + wn;
    u16* Sb = Sdst + (size_t)zb * 4194304;      // tiled [16 RB][64 T][512]g
#pragma unroll
    for (int mi = 0; mi < 4; ++mi)
#pragma unroll
        for (int r = 0; r < 4; ++r) {
            const int row = m0 + wm * 64 + mi * 16 + quad * 4 + r;
            const u64 wbits = mb[(size_t)row * 32];
            const int col0 = n0 + wn * 64 + lane15;
#pragma unroll
            for (int ni = 0; ni < 4; ++ni) {
                const int masked = (int)((wbits >> (lane15 + ni * 16)) & 1);
                const float p = masked ? 0.f : __expf(acc[mi][ni][r] * SCALE);
                Sb[tidx(row, col0 + ni * 16, 64)] = f2h_bits(p);
            }
        }
}

// ---------------- gemmO: R15 verbatim ----------------
__global__ __launch_bounds__(256) void gemmO(
    const u16* __restrict__ Ssrc, const u16* __restrict__ vt,
    float* __restrict__ outp, int b0)
{
    GEMM_PRE();
    const int zb = blockIdx.z;
    const int b = b0 + zb;
    const int hh = blockIdx.y * 4 + blockIdx.x;
    const int sl = (hh & 7) * 8 + (hh >> 3);
    const int m0 = (sl >> 2) * 128, n0 = (sl & 3) * 128;
    const u16* A = Ssrc + (size_t)zb * 4194304 + (size_t)(m0 >> 7) * 64 * 4096;
    const u16* B = vt + (size_t)b * 1048576 + (size_t)(n0 >> 7) * 64 * 4096;

    gemm_core<1, 0, 0>(A, S_DIM, B, S_DIM, S_DIM, As, Bs, acc, accS);

#pragma unroll
    for (int mi = 0; mi < 4; ++mi)
#pragma unroll
        for (int r = 0; r < 4; ++r) {
            const int row = m0 + wm * 64 + mi * 16 + quad * 4 + r;
            const float inv = 1.f / accS[mi][r];
#pragma unroll
            for (int ni = 0; ni < 4; ++ni) {
                const int col = n0 + wn * 64 + ni * 16 + lane15;
                outp[((size_t)b * S_DIM + row) * E_DIM + col] = acc[mi][ni][r] * inv;
            }
        }
}

extern "C" void kernel_launch(void* const* d_in, const int* in_sizes, int n_in,
                              void* d_out, int out_size, void* d_ws, size_t ws_size,
                              hipStream_t stream) {
    const void* x    = d_in[0];
    const int*  mask = (const int*)d_in[1];
    const void* wq   = d_in[2];
    const void* bq   = d_in[3];
    const void* wk   = d_in[4];
    const void* bk   = d_in[5];
    const void* wv   = d_in[6];
    const void* bv   = d_in[7];

    const size_t MB    = 1ull << 20;
    const size_t QSZ   = (size_t)NROWS * E_DIM;         // u16 elems per Q/K/Vt/xh
    const size_t S_PB  = (size_t)S_DIM * S_DIM;         // u16 elems per S batch
    const size_t MBITS = NWORDS * 8;                    // 4 MB

    u16* wb   = (u16*)d_ws;                             // 2 MB (weights+bias f16)
    u16* qb   = (u16*)((char*)d_ws + 2 * MB);
    u16* kb   = qb + QSZ;
    u16* vtb  = kb + QSZ;
    u64* mbit = (u64*)(vtb + QSZ);                      // 4 MB bitmask
    u16* xh   = (u16*)((char*)mbit + MBITS);            // 16.8 MB f16 x (dead after proj)
    u16* sS   = xh;                                     // S scratch aliases xh

    const size_t fixed = 2 * MB + 3 * QSZ * 2 + MBITS;  // 56.4 MB (pre-xh)
    const size_t avail = (ws_size > fixed) ? (ws_size - fixed) : 0;
    const int use_xh = avail >= (QSZ * 2 + 2 * S_PB);   // xh + >=2 S batches
    const size_t availB = avail / (S_PB * 2);
    const int P = (availB >= 8) ? 8 : (availB >= 4) ? 4 : (availB >= 2) ? 2 : 1;

    conv_w<<<dim3(128, 3), 256, 0, stream>>>(wq, wk, wv, bq, bk, bv, wb);
    conv_mask<<<2048, 256, 0, stream>>>(mask, mbit);

    if (use_xh) {
        conv_x<<<NROWS / 4, 256, 0, stream>>>(x, wq, xh);
        proj_gemm<0><<<dim3(4, 128, 3), 256, 0, stream>>>(xh, wb, qb, kb, vtb);
    } else {
        if (in_sizes[0] >= (int)(NROWS * 512 * 4))
            proj_gemm<1><<<dim3(4, 128, 3), 256, 0, stream>>>(x, wb, qb, kb, vtb);
        else
            proj_gemm<2><<<dim3(4, 128, 3), 256, 0, stream>>>(x, wb, qb, kb, vtb);
    }

    for (int p = 0; p < 8; p += P) {
        gemmS<<<dim3(16, 16, P), 256, 0, stream>>>(qb, kb, mbit, sS, p);
        gemmO<<<dim3(4, 16, P), 256, 0, stream>>>(sS, vtb, (float*)d_out, p);
    }
}

// Round 18
// 202.808 us; speedup vs baseline: 1.4374x; 1.0158x over previous
//
#include <hip/hip_runtime.h>
#include <hip/hip_bf16.h>
#include <hip/hip_fp16.h>

// MHAHead B=8,S=2048,E=512. R23: R21 + fast conv_mask (the only change).
//   R21 post-mortem: mask/gemm separation CONFIRMED (gemmS 125.5->82,
//   Mfma 17%, FETCH 139->76MB) but conv_mask itself measured ~52us
//   (2.3x its 22us BW floor): 4-deep ILP, 64 serial rounds/wave.
//   R23: conv_mask grid 2048->4096 blocks (32 words/wave) and 8-deep
//   unroll (8x256B coalesced loads in flight -> 8 ballots -> lane0
//   stores 8 consecutive u64). Everything else R21-verbatim.

typedef unsigned short u16;
typedef unsigned long long u64;
typedef __attribute__((ext_vector_type(8))) short short8;
typedef __attribute__((ext_vector_type(8))) _Float16 half8;
typedef __attribute__((ext_vector_type(4))) float float4v;

#define S_DIM 2048
#define E_DIM 512
#define NROWS (8 * S_DIM)
#define SCALE 0.044194173824159216f
#define NWORDS ((size_t)8 * S_DIM * S_DIM / 64)   // 524288 u64 words (4 MB)

__device__ __forceinline__ float4v mfma16(short8 a, short8 b, float4v c) {
    return __builtin_amdgcn_mfma_f32_16x16x32_f16(
        __builtin_bit_cast(half8, a), __builtin_bit_cast(half8, b), c, 0, 0, 0);
}
__device__ __forceinline__ float bf2f(unsigned int u) {
    union { unsigned int i; float f; } v; v.i = u << 16; return v.f;
}
__device__ __forceinline__ u16 f2h_bits(float f) {
    union { _Float16 h; u16 u; } v; v.h = (_Float16)f; return v.u;
}
__device__ __forceinline__ float h2f(u16 u) {
    union { u16 u; _Float16 h; } v; v.u = u; return (float)v.h;
}
// tiled u16 index for element (row, col) in a [rows][K] matrix with NT=K/32 tiles
__device__ __forceinline__ size_t tidx(int row, int col, int NT) {
    const int rr = row & 127;
    const int g = 4 * rr + (((col & 31) >> 3) ^ ((rr >> 1) & 3));
    return ((size_t)((row >> 7) * NT + (col >> 5)) * 512 + g) * 8 + (col & 7);
}
__device__ __forceinline__ int detect_bf16(const void* wp) {
    const u16* w = (const u16*)wp;
    int cnt = 0;
    for (int i = 0; i < 64; ++i) {
        int e = (w[2 * i] >> 7) & 0xff;
        cnt += (e >= 100 && e <= 131) ? 1 : 0;
    }
    return cnt >= 40;
}
__device__ __forceinline__ void load8(const void* base, size_t idx, int isbf, float* f) {
    if (isbf) {
        uint4 v = *(const uint4*)((const u16*)base + idx);
        f[0] = bf2f(v.x & 0xffffu); f[1] = bf2f(v.x >> 16);
        f[2] = bf2f(v.y & 0xffffu); f[3] = bf2f(v.y >> 16);
        f[4] = bf2f(v.z & 0xffffu); f[5] = bf2f(v.z >> 16);
        f[6] = bf2f(v.w & 0xffffu); f[7] = bf2f(v.w >> 16);
    } else {
        const float* p = (const float*)base + idx;
        float4 a = *(const float4*)p;
        float4 b = *(const float4*)(p + 4);
        f[0] = a.x; f[1] = a.y; f[2] = a.z; f[3] = a.w;
        f[4] = b.x; f[5] = b.y; f[6] = b.z; f[7] = b.w;
    }
}
__device__ __forceinline__ float load1(const void* base, size_t idx, int isbf) {
    return isbf ? bf2f(((const u16*)base)[idx]) : ((const float*)base)[idx];
}

// async 16B global -> LDS (per-lane src, wave-uniform LDS base + lane*16)
__device__ __forceinline__ void gld16(const u16* g, u16* l) {
    __builtin_amdgcn_global_load_lds(
        (const __attribute__((address_space(1))) void*)g,
        (__attribute__((address_space(3))) void*)l, 16, 0, 0);
}

// row-major staging fallback (fp32/bf16 x input): reg-staged convert
template<int C>
__device__ __forceinline__ void stage(const void* g, size_t off, u16* lds) {
    if constexpr (C == 1) {
        const float* p = (const float*)g + off;
        float4 a = *(const float4*)p;
        float4 b = *(const float4*)(p + 4);
        union { u16 h[8]; short8 v; } pk;
        pk.h[0] = f2h_bits(a.x); pk.h[1] = f2h_bits(a.y);
        pk.h[2] = f2h_bits(a.z); pk.h[3] = f2h_bits(a.w);
        pk.h[4] = f2h_bits(b.x); pk.h[5] = f2h_bits(b.y);
        pk.h[6] = f2h_bits(b.z); pk.h[7] = f2h_bits(b.w);
        *(short8*)lds = pk.v;
    } else {
        uint4 v = *(const uint4*)((const u16*)g + off);
        unsigned int uu[4] = {v.x, v.y, v.z, v.w};
        union { u16 h[8]; short8 v8; } pk;
#pragma unroll
        for (int j = 0; j < 4; ++j) {
            pk.h[2 * j]     = f2h_bits(bf2f(uu[j] & 0xffffu));
            pk.h[2 * j + 1] = f2h_bits(bf2f(uu[j] >> 16));
        }
        *(short8*)lds = pk.v8;
    }
}

// ---------------- conversion kernels (read inputs, write ws) ----------------
__global__ __launch_bounds__(256) void conv_w(
    const void* w0, const void* w1, const void* w2,
    const void* b0, const void* b1, const void* b2, u16* wb)
{
    const int z = blockIdx.y;
    const void* w = (z == 0) ? w0 : (z == 1) ? w1 : w2;
    const void* bb = (z == 0) ? b0 : (z == 1) ? b1 : b2;
    const int isbf = detect_bf16(w0);
    const size_t idx = ((size_t)blockIdx.x * 256 + threadIdx.x) * 8;
    const int n = (int)(idx >> 9), kk = (int)(idx & 511);
    float f[8];
    load8(w, idx, isbf, f);
    union { u16 h[8]; uint4 v; } pk;
#pragma unroll
    for (int j = 0; j < 8; ++j) pk.h[j] = f2h_bits(f[j]);
    *(uint4*)(wb + (size_t)z * 262144 + tidx(n, kk, 16)) = pk.v;
    if (blockIdx.x == 0) {
        u16* bbase = wb + 3 * 262144 + z * 512;
#pragma unroll
        for (int j = 0; j < 2; ++j) {
            int i = threadIdx.x * 2 + j;
            bbase[i] = f2h_bits(load1(bb, i, isbf));
        }
    }
}

// mask int32 -> bit-packed u64 (bit l of word w = mask[w*64+l] > 0).
// 4096 blocks x 4 waves x 32 words; 8-deep coalesced loads (2KB in flight),
// 8 ballots, lane0 stores 8 consecutive u64 (64B span). BW-bound.
__global__ __launch_bounds__(256) void conv_mask(
    const int* __restrict__ mask, u64* __restrict__ mbits)
{
    const int gw = blockIdx.x * 4 + (threadIdx.x >> 6);   // global wave id
    const int l = threadIdx.x & 63;
    const size_t w0 = (size_t)gw * 32;
#pragma unroll 1
    for (int i = 0; i < 32; i += 8) {
        int m[8];
#pragma unroll
        for (int j = 0; j < 8; ++j)
            m[j] = mask[(w0 + i + j) * 64 + l];
        u64 b[8];
#pragma unroll
        for (int j = 0; j < 8; ++j)
            b[j] = __ballot(m[j] > 0);
        if (l == 0) {
#pragma unroll
            for (int j = 0; j < 8; ++j)
                mbits[w0 + i + j] = b[j];
        }
    }
}

// x fp32/bf16 -> f16 TILED [RB 128][16 tiles][512 granules] in ws.
__global__ __launch_bounds__(256) void conv_x(
    const void* x, const void* wq_orig, u16* xh)
{
    const int w = threadIdx.x >> 6, l = threadIdx.x & 63;
    const int row = blockIdx.x * 4 + w;
    union { u16 h[8]; uint4 v; } pk;
    if (detect_bf16(wq_orig)) {
        uint4 v = *(const uint4*)((const u16*)x + (size_t)row * 512 + l * 8);
        unsigned int uu[4] = {v.x, v.y, v.z, v.w};
#pragma unroll
        for (int j = 0; j < 4; ++j) {
            pk.h[2 * j]     = f2h_bits(bf2f(uu[j] & 0xffffu));
            pk.h[2 * j + 1] = f2h_bits(bf2f(uu[j] >> 16));
        }
    } else {
        const float* src = (const float*)x + (size_t)row * 512 + l * 8;
        float4 a = *(const float4*)src;
        float4 b = *(const float4*)(src + 4);
        pk.h[0] = f2h_bits(a.x); pk.h[1] = f2h_bits(a.y);
        pk.h[2] = f2h_bits(a.z); pk.h[3] = f2h_bits(a.w);
        pk.h[4] = f2h_bits(b.x); pk.h[5] = f2h_bits(b.y);
        pk.h[6] = f2h_bits(b.z); pk.h[7] = f2h_bits(b.w);
    }
    *(uint4*)(xh + tidx(row, l * 8, 16)) = pk.v;
}

// ---------------- shared GEMM core (R15: BK=32, 4 waves, tiled gld16) -------
template<int ONES, int CA, int CB>
__device__ __forceinline__ void gemm_core(
    const void* __restrict__ A, int sA, const void* __restrict__ B, int sB, int K,
    u16* As, u16* Bs, float4v acc[4][4], float4v accS[4])
{
    const int t = threadIdx.x;
    const int w = t >> 6, l = t & 63;
    const int lane15 = l & 15, quad = l >> 4;
    const int wm = w & 1, wn = w >> 1;

    short8 ones;
#pragma unroll
    for (int j = 0; j < 8; ++j) ones[j] = (short)0x3C00;   // f16 1.0

    for (int kt = 0; kt < K; kt += 32) {
        const int kti = kt >> 5;
        __syncthreads();
#pragma unroll
        for (int i = 0; i < 2; ++i) {
            const int fg = w * 128 + i * 64 + l;
            const int r = fg >> 2;
            const int kq = (fg & 3) ^ ((r >> 1) & 3);
            if constexpr (CA == 0)
                gld16((const u16*)A + (size_t)kti * 4096 + fg * 8, As + fg * 8);
            else
                stage<CA>(A, (size_t)r * sA + kt + kq * 8, As + fg * 8);
            if constexpr (CB == 0)
                gld16((const u16*)B + (size_t)kti * 4096 + fg * 8, Bs + fg * 8);
            else
                stage<CB>(B, (size_t)r * sB + kt + kq * 8, Bs + fg * 8);
        }
        __syncthreads();

        short8 af[4], bf[4];
#pragma unroll
        for (int mi = 0; mi < 4; ++mi) {
            const int r = wm * 64 + mi * 16 + lane15;
            af[mi] = *(const short8*)&As[(4 * r + (quad ^ ((r >> 1) & 3))) * 8];
        }
#pragma unroll
        for (int ni = 0; ni < 4; ++ni) {
            const int r = wn * 64 + ni * 16 + lane15;
            bf[ni] = *(const short8*)&Bs[(4 * r + (quad ^ ((r >> 1) & 3))) * 8];
        }
#pragma unroll
        for (int mi = 0; mi < 4; ++mi) {
#pragma unroll
            for (int ni = 0; ni < 4; ++ni)
                acc[mi][ni] = mfma16(af[mi], bf[ni], acc[mi][ni]);
            if (ONES) accS[mi] = mfma16(af[mi], ones, accS[mi]);
        }
    }
}

#define GEMM_PRE()                                                     \
    __shared__ u16 As[4096] __attribute__((aligned(16)));              \
    __shared__ u16 Bs[4096] __attribute__((aligned(16)));              \
    const int t = threadIdx.x;                                         \
    const int w = t >> 6, l = t & 63;                                  \
    const int lane15 = l & 15, quad = l >> 4;                          \
    const int wm = w & 1, wn = w >> 1;                                 \
    (void)l; (void)w;                                                  \
    float4v acc[4][4];                                                 \
    float4v accS[4];                                                   \
    _Pragma("unroll") for (int mi = 0; mi < 4; ++mi) {                 \
        accS[mi] = (float4v){0.f, 0.f, 0.f, 0.f};                      \
        _Pragma("unroll") for (int ni = 0; ni < 4; ++ni)               \
            acc[mi][ni] = (float4v){0.f, 0.f, 0.f, 0.f};               \
    }

// ---------------- proj: Q, K, Vt (outputs tiled; R15 verbatim) --------------
template<int XM>
__global__ __launch_bounds__(256) void proj_gemm(
    const void* __restrict__ xsrc, const u16* __restrict__ wb,
    u16* __restrict__ qb, u16* __restrict__ kb, u16* __restrict__ vt)
{
    GEMM_PRE();
    const int z = blockIdx.z;
    const int hh = blockIdx.y * 4 + blockIdx.x;
    const int sl = (hh & 7) * 64 + (hh >> 3);
    const int ty = sl >> 2, tx = sl & 3;
    const u16* bias = wb + 3 * 262144 + z * 512;

    int m0, n0;
    if (z < 2) { m0 = ty * 128; n0 = tx * 128; }
    else       { m0 = tx * 128; n0 = ty * 128; }

    if (z < 2) {
        const void* B = wb + (size_t)z * 262144 + (size_t)(n0 >> 7) * 16 * 4096;
        if (XM == 0) {
            const void* A = (const u16*)xsrc + (size_t)(m0 >> 7) * 16 * 4096;
            gemm_core<0, 0, 0>(A, 512, B, 512, 512, As, Bs, acc, accS);
        } else if (XM == 1) {
            const void* A = (const float*)xsrc + (size_t)m0 * 512;
            gemm_core<0, 1, 0>(A, 512, B, 512, 512, As, Bs, acc, accS);
        } else {
            const void* A = (const u16*)xsrc + (size_t)m0 * 512;
            gemm_core<0, 2, 0>(A, 512, B, 512, 512, As, Bs, acc, accS);
        }
    } else {
        const void* A = wb + (size_t)2 * 262144 + (size_t)(m0 >> 7) * 16 * 4096;
        if (XM == 0) {
            const void* B = (const u16*)xsrc + (size_t)(n0 >> 7) * 16 * 4096;
            gemm_core<0, 0, 0>(A, 512, B, 512, 512, As, Bs, acc, accS);
        } else if (XM == 1) {
            const void* B = (const float*)xsrc + (size_t)n0 * 512;
            gemm_core<0, 0, 1>(A, 512, B, 512, 512, As, Bs, acc, accS);
        } else {
            const void* B = (const u16*)xsrc + (size_t)n0 * 512;
            gemm_core<0, 0, 2>(A, 512, B, 512, 512, As, Bs, acc, accS);
        }
    }

    if (z < 2) {
        u16* dst = z ? kb : qb;                 // tiled [rows/128][16][512]g
        float bcol[4];
#pragma unroll
        for (int ni = 0; ni < 4; ++ni)
            bcol[ni] = h2f(bias[n0 + wn * 64 + ni * 16 + lane15]);
#pragma unroll
        for (int mi = 0; mi < 4; ++mi)
#pragma unroll
            for (int ni = 0; ni < 4; ++ni)
#pragma unroll
                for (int r = 0; r < 4; ++r) {
                    const int row = m0 + wm * 64 + mi * 16 + quad * 4 + r;
                    const int col = n0 + wn * 64 + ni * 16 + lane15;
                    dst[tidx(row, col, 16)] = f2h_bits(acc[mi][ni][r] + bcol[ni]);
                }
    } else {
        // Vt tiled per batch: [b][4 RBe][64 T][512]g ; rows = e, K = token
#pragma unroll
        for (int mi = 0; mi < 4; ++mi)
#pragma unroll
            for (int r = 0; r < 4; ++r) {
                const int e = m0 + wm * 64 + mi * 16 + quad * 4 + r;      // 0..511
                const float bias_e = h2f(bias[e]);
#pragma unroll
                for (int ni = 0; ni < 4; ++ni) {
                    const int tok = n0 + wn * 64 + ni * 16 + lane15;
                    const int b = tok >> 11, kk = tok & 2047;
                    vt[(size_t)b * 1048576 + tidx(e, kk, 64)] =
                        f2h_bits(acc[mi][ni][r] + bias_e);
                }
            }
    }
}

// ---------------- gemmS: gemm + bitmask epilogue (no mask stream inside) ----
__global__ __launch_bounds__(256) void gemmS(
    const u16* __restrict__ qb, const u16* __restrict__ kb,
    const u64* __restrict__ mbits, u16* __restrict__ Sdst, int b0)
{
    GEMM_PRE();
    const int zb = blockIdx.z;
    const int b = b0 + zb;
    const int hh = blockIdx.y * 16 + blockIdx.x;
    const int sl = (hh & 7) * 32 + (hh >> 3);
    const int m0 = (sl >> 4) * 128, n0 = (sl & 15) * 128;

    const u16* A = qb + (size_t)((b * S_DIM + m0) >> 7) * 16 * 4096;
    const u16* B = kb + (size_t)((b * S_DIM + n0) >> 7) * 16 * 4096;
    gemm_core<0, 0, 0>(A, 512, B, 512, 512, As, Bs, acc, accS);

    // bit word for this wave's 64-col window: cols [n0+wn*64, +64)
    const u64* mb = mbits + (size_t)b * S_DIM * 32 + (n0 >> 6) + wn;
    u16* Sb = Sdst + (size_t)zb * 4194304;      // tiled [16 RB][64 T][512]g
#pragma unroll
    for (int mi = 0; mi < 4; ++mi)
#pragma unroll
        for (int r = 0; r < 4; ++r) {
            const int row = m0 + wm * 64 + mi * 16 + quad * 4 + r;
            const u64 wbits = mb[(size_t)row * 32];
            const int col0 = n0 + wn * 64 + lane15;
#pragma unroll
            for (int ni = 0; ni < 4; ++ni) {
                const int masked = (int)((wbits >> (lane15 + ni * 16)) & 1);
                const float p = masked ? 0.f : __expf(acc[mi][ni][r] * SCALE);
                Sb[tidx(row, col0 + ni * 16, 64)] = f2h_bits(p);
            }
        }
}

// ---------------- gemmO: R15 verbatim ----------------
__global__ __launch_bounds__(256) void gemmO(
    const u16* __restrict__ Ssrc, const u16* __restrict__ vt,
    float* __restrict__ outp, int b0)
{
    GEMM_PRE();
    const int zb = blockIdx.z;
    const int b = b0 + zb;
    const int hh = blockIdx.y * 4 + blockIdx.x;
    const int sl = (hh & 7) * 8 + (hh >> 3);
    const int m0 = (sl >> 2) * 128, n0 = (sl & 3) * 128;
    const u16* A = Ssrc + (size_t)zb * 4194304 + (size_t)(m0 >> 7) * 64 * 4096;
    const u16* B = vt + (size_t)b * 1048576 + (size_t)(n0 >> 7) * 64 * 4096;

    gemm_core<1, 0, 0>(A, S_DIM, B, S_DIM, S_DIM, As, Bs, acc, accS);

#pragma unroll
    for (int mi = 0; mi < 4; ++mi)
#pragma unroll
        for (int r = 0; r < 4; ++r) {
            const int row = m0 + wm * 64 + mi * 16 + quad * 4 + r;
            const float inv = 1.f / accS[mi][r];
#pragma unroll
            for (int ni = 0; ni < 4; ++ni) {
                const int col = n0 + wn * 64 + ni * 16 + lane15;
                outp[((size_t)b * S_DIM + row) * E_DIM + col] = acc[mi][ni][r] * inv;
            }
        }
}

extern "C" void kernel_launch(void* const* d_in, const int* in_sizes, int n_in,
                              void* d_out, int out_size, void* d_ws, size_t ws_size,
                              hipStream_t stream) {
    const void* x    = d_in[0];
    const int*  mask = (const int*)d_in[1];
    const void* wq   = d_in[2];
    const void* bq   = d_in[3];
    const void* wk   = d_in[4];
    const void* bk   = d_in[5];
    const void* wv   = d_in[6];
    const void* bv   = d_in[7];

    const size_t MB    = 1ull << 20;
    const size_t QSZ   = (size_t)NROWS * E_DIM;         // u16 elems per Q/K/Vt/xh
    const size_t S_PB  = (size_t)S_DIM * S_DIM;         // u16 elems per S batch
    const size_t MBITS = NWORDS * 8;                    // 4 MB

    u16* wb   = (u16*)d_ws;                             // 2 MB (weights+bias f16)
    u16* qb   = (u16*)((char*)d_ws + 2 * MB);
    u16* kb   = qb + QSZ;
    u16* vtb  = kb + QSZ;
    u64* mbit = (u64*)(vtb + QSZ);                      // 4 MB bitmask
    u16* xh   = (u16*)((char*)mbit + MBITS);            // 16.8 MB f16 x (dead after proj)
    u16* sS   = xh;                                     // S scratch aliases xh

    const size_t fixed = 2 * MB + 3 * QSZ * 2 + MBITS;  // 56.4 MB (pre-xh)
    const size_t avail = (ws_size > fixed) ? (ws_size - fixed) : 0;
    const int use_xh = avail >= (QSZ * 2 + 2 * S_PB);   // xh + >=2 S batches
    const size_t availB = avail / (S_PB * 2);
    const int P = (availB >= 8) ? 8 : (availB >= 4) ? 4 : (availB >= 2) ? 2 : 1;

    conv_w<<<dim3(128, 3), 256, 0, stream>>>(wq, wk, wv, bq, bk, bv, wb);
    conv_mask<<<4096, 256, 0, stream>>>(mask, mbit);

    if (use_xh) {
        conv_x<<<NROWS / 4, 256, 0, stream>>>(x, wq, xh);
        proj_gemm<0><<<dim3(4, 128, 3), 256, 0, stream>>>(xh, wb, qb, kb, vtb);
    } else {
        if (in_sizes[0] >= (int)(NROWS * 512 * 4))
            proj_gemm<1><<<dim3(4, 128, 3), 256, 0, stream>>>(x, wb, qb, kb, vtb);
        else
            proj_gemm<2><<<dim3(4, 128, 3), 256, 0, stream>>>(x, wb, qb, kb, vtb);
    }

    for (int p = 0; p < 8; p += P) {
        gemmS<<<dim3(16, 16, P), 256, 0, stream>>>(qb, kb, mbit, sS, p);
        gemmO<<<dim3(4, 16, P), 256, 0, stream>>>(sS, vtb, (float*)d_out, p);
    }
}

// Round 19
// 200.671 us; speedup vs baseline: 1.4527x; 1.0106x over previous
//
#include <hip/hip_runtime.h>
#include <hip/hip_bf16.h>
#include <hip/hip_fp16.h>

// MHAHead B=8,S=2048,E=512. R24: vectorized conv_mask (uint4 loads), only change.
//   R23 post-mortem: conv_mask stuck ~49us (2.8 TB/s) -- scalar 4B/lane loads
//   (G13 violation). gemmS stable 81us, gemmO ~27us (timestamp gap).
//   R24: conv_mask loads 16B/lane (8KB/wave in flight, 8 chunks unrolled);
//   bitmask BIT ORDER redefined to the ballot-natural permutation
//   p(e) = (e&3)*16 + (e>>2); gemmS epilogue reads bit p0+4*ni where
//   p0 = (lane15&3)*16 + (lane15>>2) -- same cost. All else R23-verbatim.

typedef unsigned short u16;
typedef unsigned long long u64;
typedef __attribute__((ext_vector_type(8))) short short8;
typedef __attribute__((ext_vector_type(8))) _Float16 half8;
typedef __attribute__((ext_vector_type(4))) float float4v;

#define S_DIM 2048
#define E_DIM 512
#define NROWS (8 * S_DIM)
#define SCALE 0.044194173824159216f
#define NWORDS ((size_t)8 * S_DIM * S_DIM / 64)   // 524288 u64 words (4 MB)

__device__ __forceinline__ float4v mfma16(short8 a, short8 b, float4v c) {
    return __builtin_amdgcn_mfma_f32_16x16x32_f16(
        __builtin_bit_cast(half8, a), __builtin_bit_cast(half8, b), c, 0, 0, 0);
}
__device__ __forceinline__ float bf2f(unsigned int u) {
    union { unsigned int i; float f; } v; v.i = u << 16; return v.f;
}
__device__ __forceinline__ u16 f2h_bits(float f) {
    union { _Float16 h; u16 u; } v; v.h = (_Float16)f; return v.u;
}
__device__ __forceinline__ float h2f(u16 u) {
    union { u16 u; _Float16 h; } v; v.u = u; return (float)v.h;
}
// tiled u16 index for element (row, col) in a [rows][K] matrix with NT=K/32 tiles
__device__ __forceinline__ size_t tidx(int row, int col, int NT) {
    const int rr = row & 127;
    const int g = 4 * rr + (((col & 31) >> 3) ^ ((rr >> 1) & 3));
    return ((size_t)((row >> 7) * NT + (col >> 5)) * 512 + g) * 8 + (col & 7);
}
__device__ __forceinline__ int detect_bf16(const void* wp) {
    const u16* w = (const u16*)wp;
    int cnt = 0;
    for (int i = 0; i < 64; ++i) {
        int e = (w[2 * i] >> 7) & 0xff;
        cnt += (e >= 100 && e <= 131) ? 1 : 0;
    }
    return cnt >= 40;
}
__device__ __forceinline__ void load8(const void* base, size_t idx, int isbf, float* f) {
    if (isbf) {
        uint4 v = *(const uint4*)((const u16*)base + idx);
        f[0] = bf2f(v.x & 0xffffu); f[1] = bf2f(v.x >> 16);
        f[2] = bf2f(v.y & 0xffffu); f[3] = bf2f(v.y >> 16);
        f[4] = bf2f(v.z & 0xffffu); f[5] = bf2f(v.z >> 16);
        f[6] = bf2f(v.w & 0xffffu); f[7] = bf2f(v.w >> 16);
    } else {
        const float* p = (const float*)base + idx;
        float4 a = *(const float4*)p;
        float4 b = *(const float4*)(p + 4);
        f[0] = a.x; f[1] = a.y; f[2] = a.z; f[3] = a.w;
        f[4] = b.x; f[5] = b.y; f[6] = b.z; f[7] = b.w;
    }
}
__device__ __forceinline__ float load1(const void* base, size_t idx, int isbf) {
    return isbf ? bf2f(((const u16*)base)[idx]) : ((const float*)base)[idx];
}

// async 16B global -> LDS (per-lane src, wave-uniform LDS base + lane*16)
__device__ __forceinline__ void gld16(const u16* g, u16* l) {
    __builtin_amdgcn_global_load_lds(
        (const __attribute__((address_space(1))) void*)g,
        (__attribute__((address_space(3))) void*)l, 16, 0, 0);
}

// row-major staging fallback (fp32/bf16 x input): reg-staged convert
template<int C>
__device__ __forceinline__ void stage(const void* g, size_t off, u16* lds) {
    if constexpr (C == 1) {
        const float* p = (const float*)g + off;
        float4 a = *(const float4*)p;
        float4 b = *(const float4*)(p + 4);
        union { u16 h[8]; short8 v; } pk;
        pk.h[0] = f2h_bits(a.x); pk.h[1] = f2h_bits(a.y);
        pk.h[2] = f2h_bits(a.z); pk.h[3] = f2h_bits(a.w);
        pk.h[4] = f2h_bits(b.x); pk.h[5] = f2h_bits(b.y);
        pk.h[6] = f2h_bits(b.z); pk.h[7] = f2h_bits(b.w);
        *(short8*)lds = pk.v;
    } else {
        uint4 v = *(const uint4*)((const u16*)g + off);
        unsigned int uu[4] = {v.x, v.y, v.z, v.w};
        union { u16 h[8]; short8 v8; } pk;
#pragma unroll
        for (int j = 0; j < 4; ++j) {
            pk.h[2 * j]     = f2h_bits(bf2f(uu[j] & 0xffffu));
            pk.h[2 * j + 1] = f2h_bits(bf2f(uu[j] >> 16));
        }
        *(short8*)lds = pk.v8;
    }
}

// ---------------- conversion kernels (read inputs, write ws) ----------------
__global__ __launch_bounds__(256) void conv_w(
    const void* w0, const void* w1, const void* w2,
    const void* b0, const void* b1, const void* b2, u16* wb)
{
    const int z = blockIdx.y;
    const void* w = (z == 0) ? w0 : (z == 1) ? w1 : w2;
    const void* bb = (z == 0) ? b0 : (z == 1) ? b1 : b2;
    const int isbf = detect_bf16(w0);
    const size_t idx = ((size_t)blockIdx.x * 256 + threadIdx.x) * 8;
    const int n = (int)(idx >> 9), kk = (int)(idx & 511);
    float f[8];
    load8(w, idx, isbf, f);
    union { u16 h[8]; uint4 v; } pk;
#pragma unroll
    for (int j = 0; j < 8; ++j) pk.h[j] = f2h_bits(f[j]);
    *(uint4*)(wb + (size_t)z * 262144 + tidx(n, kk, 16)) = pk.v;
    if (blockIdx.x == 0) {
        u16* bbase = wb + 3 * 262144 + z * 512;
#pragma unroll
        for (int j = 0; j < 2; ++j) {
            int i = threadIdx.x * 2 + j;
            bbase[i] = f2h_bits(load1(bb, i, isbf));
        }
    }
}

// mask int32 -> bit-packed u64, PERMUTED bit order: within a 64-elem word,
// element e sits at bit p(e) = (e&3)*16 + (e>>2).
// Wave processes 8 chunks of 256 elems (uint4/lane, 8KB in flight, 32 ballots).
__global__ __launch_bounds__(256) void conv_mask(
    const int* __restrict__ mask, u64* __restrict__ mbits)
{
    const int gw = blockIdx.x * 4 + (threadIdx.x >> 6);   // global wave id
    const int l = threadIdx.x & 63;
    const size_t c0 = (size_t)gw * 8;                     // first chunk (of 131072)

    uint4 v[8];
#pragma unroll
    for (int i = 0; i < 8; ++i)
        v[i] = *(const uint4*)(mask + (c0 + i) * 256 + l * 4);

    u64 b[32];
#pragma unroll
    for (int i = 0; i < 8; ++i) {
        b[4 * i + 0] = __ballot((int)v[i].x > 0);
        b[4 * i + 1] = __ballot((int)v[i].y > 0);
        b[4 * i + 2] = __ballot((int)v[i].z > 0);
        b[4 * i + 3] = __ballot((int)v[i].w > 0);
    }

#pragma unroll
    for (int ch = 0; ch < 8; ++ch) {
        if ((l >> 2) == ch) {                             // 4 lanes per chunk
            const int g = l & 3;                          // word within chunk
            const int sh = 16 * g;
            const u64 W = ((b[4 * ch + 0] >> sh) & 0xFFFFull)
                        | (((b[4 * ch + 1] >> sh) & 0xFFFFull) << 16)
                        | (((b[4 * ch + 2] >> sh) & 0xFFFFull) << 32)
                        | (((b[4 * ch + 3] >> sh) & 0xFFFFull) << 48);
            mbits[(c0 + ch) * 4 + g] = W;
        }
    }
}

// x fp32/bf16 -> f16 TILED [RB 128][16 tiles][512 granules] in ws.
__global__ __launch_bounds__(256) void conv_x(
    const void* x, const void* wq_orig, u16* xh)
{
    const int w = threadIdx.x >> 6, l = threadIdx.x & 63;
    const int row = blockIdx.x * 4 + w;
    union { u16 h[8]; uint4 v; } pk;
    if (detect_bf16(wq_orig)) {
        uint4 v = *(const uint4*)((const u16*)x + (size_t)row * 512 + l * 8);
        unsigned int uu[4] = {v.x, v.y, v.z, v.w};
#pragma unroll
        for (int j = 0; j < 4; ++j) {
            pk.h[2 * j]     = f2h_bits(bf2f(uu[j] & 0xffffu));
            pk.h[2 * j + 1] = f2h_bits(bf2f(uu[j] >> 16));
        }
    } else {
        const float* src = (const float*)x + (size_t)row * 512 + l * 8;
        float4 a = *(const float4*)src;
        float4 b = *(const float4*)(src + 4);
        pk.h[0] = f2h_bits(a.x); pk.h[1] = f2h_bits(a.y);
        pk.h[2] = f2h_bits(a.z); pk.h[3] = f2h_bits(a.w);
        pk.h[4] = f2h_bits(b.x); pk.h[5] = f2h_bits(b.y);
        pk.h[6] = f2h_bits(b.z); pk.h[7] = f2h_bits(b.w);
    }
    *(uint4*)(xh + tidx(row, l * 8, 16)) = pk.v;
}

// ---------------- shared GEMM core (R15: BK=32, 4 waves, tiled gld16) -------
template<int ONES, int CA, int CB>
__device__ __forceinline__ void gemm_core(
    const void* __restrict__ A, int sA, const void* __restrict__ B, int sB, int K,
    u16* As, u16* Bs, float4v acc[4][4], float4v accS[4])
{
    const int t = threadIdx.x;
    const int w = t >> 6, l = t & 63;
    const int lane15 = l & 15, quad = l >> 4;
    const int wm = w & 1, wn = w >> 1;

    short8 ones;
#pragma unroll
    for (int j = 0; j < 8; ++j) ones[j] = (short)0x3C00;   // f16 1.0

    for (int kt = 0; kt < K; kt += 32) {
        const int kti = kt >> 5;
        __syncthreads();
#pragma unroll
        for (int i = 0; i < 2; ++i) {
            const int fg = w * 128 + i * 64 + l;
            const int r = fg >> 2;
            const int kq = (fg & 3) ^ ((r >> 1) & 3);
            if constexpr (CA == 0)
                gld16((const u16*)A + (size_t)kti * 4096 + fg * 8, As + fg * 8);
            else
                stage<CA>(A, (size_t)r * sA + kt + kq * 8, As + fg * 8);
            if constexpr (CB == 0)
                gld16((const u16*)B + (size_t)kti * 4096 + fg * 8, Bs + fg * 8);
            else
                stage<CB>(B, (size_t)r * sB + kt + kq * 8, Bs + fg * 8);
        }
        __syncthreads();

        short8 af[4], bf[4];
#pragma unroll
        for (int mi = 0; mi < 4; ++mi) {
            const int r = wm * 64 + mi * 16 + lane15;
            af[mi] = *(const short8*)&As[(4 * r + (quad ^ ((r >> 1) & 3))) * 8];
        }
#pragma unroll
        for (int ni = 0; ni < 4; ++ni) {
            const int r = wn * 64 + ni * 16 + lane15;
            bf[ni] = *(const short8*)&Bs[(4 * r + (quad ^ ((r >> 1) & 3))) * 8];
        }
#pragma unroll
        for (int mi = 0; mi < 4; ++mi) {
#pragma unroll
            for (int ni = 0; ni < 4; ++ni)
                acc[mi][ni] = mfma16(af[mi], bf[ni], acc[mi][ni]);
            if (ONES) accS[mi] = mfma16(af[mi], ones, accS[mi]);
        }
    }
}

#define GEMM_PRE()                                                     \
    __shared__ u16 As[4096] __attribute__((aligned(16)));              \
    __shared__ u16 Bs[4096] __attribute__((aligned(16)));              \
    const int t = threadIdx.x;                                         \
    const int w = t >> 6, l = t & 63;                                  \
    const int lane15 = l & 15, quad = l >> 4;                          \
    const int wm = w & 1, wn = w >> 1;                                 \
    (void)l; (void)w;                                                  \
    float4v acc[4][4];                                                 \
    float4v accS[4];                                                   \
    _Pragma("unroll") for (int mi = 0; mi < 4; ++mi) {                 \
        accS[mi] = (float4v){0.f, 0.f, 0.f, 0.f};                      \
        _Pragma("unroll") for (int ni = 0; ni < 4; ++ni)               \
            acc[mi][ni] = (float4v){0.f, 0.f, 0.f, 0.f};               \
    }

// ---------------- proj: Q, K, Vt (outputs tiled; R15 verbatim) --------------
template<int XM>
__global__ __launch_bounds__(256) void proj_gemm(
    const void* __restrict__ xsrc, const u16* __restrict__ wb,
    u16* __restrict__ qb, u16* __restrict__ kb, u16* __restrict__ vt)
{
    GEMM_PRE();
    const int z = blockIdx.z;
    const int hh = blockIdx.y * 4 + blockIdx.x;
    const int sl = (hh & 7) * 64 + (hh >> 3);
    const int ty = sl >> 2, tx = sl & 3;
    const u16* bias = wb + 3 * 262144 + z * 512;

    int m0, n0;
    if (z < 2) { m0 = ty * 128; n0 = tx * 128; }
    else       { m0 = tx * 128; n0 = ty * 128; }

    if (z < 2) {
        const void* B = wb + (size_t)z * 262144 + (size_t)(n0 >> 7) * 16 * 4096;
        if (XM == 0) {
            const void* A = (const u16*)xsrc + (size_t)(m0 >> 7) * 16 * 4096;
            gemm_core<0, 0, 0>(A, 512, B, 512, 512, As, Bs, acc, accS);
        } else if (XM == 1) {
            const void* A = (const float*)xsrc + (size_t)m0 * 512;
            gemm_core<0, 1, 0>(A, 512, B, 512, 512, As, Bs, acc, accS);
        } else {
            const void* A = (const u16*)xsrc + (size_t)m0 * 512;
            gemm_core<0, 2, 0>(A, 512, B, 512, 512, As, Bs, acc, accS);
        }
    } else {
        const void* A = wb + (size_t)2 * 262144 + (size_t)(m0 >> 7) * 16 * 4096;
        if (XM == 0) {
            const void* B = (const u16*)xsrc + (size_t)(n0 >> 7) * 16 * 4096;
            gemm_core<0, 0, 0>(A, 512, B, 512, 512, As, Bs, acc, accS);
        } else if (XM == 1) {
            const void* B = (const float*)xsrc + (size_t)n0 * 512;
            gemm_core<0, 0, 1>(A, 512, B, 512, 512, As, Bs, acc, accS);
        } else {
            const void* B = (const u16*)xsrc + (size_t)n0 * 512;
            gemm_core<0, 0, 2>(A, 512, B, 512, 512, As, Bs, acc, accS);
        }
    }

    if (z < 2) {
        u16* dst = z ? kb : qb;                 // tiled [rows/128][16][512]g
        float bcol[4];
#pragma unroll
        for (int ni = 0; ni < 4; ++ni)
            bcol[ni] = h2f(bias[n0 + wn * 64 + ni * 16 + lane15]);
#pragma unroll
        for (int mi = 0; mi < 4; ++mi)
#pragma unroll
            for (int ni = 0; ni < 4; ++ni)
#pragma unroll
                for (int r = 0; r < 4; ++r) {
                    const int row = m0 + wm * 64 + mi * 16 + quad * 4 + r;
                    const int col = n0 + wn * 64 + ni * 16 + lane15;
                    dst[tidx(row, col, 16)] = f2h_bits(acc[mi][ni][r] + bcol[ni]);
                }
    } else {
        // Vt tiled per batch: [b][4 RBe][64 T][512]g ; rows = e, K = token
#pragma unroll
        for (int mi = 0; mi < 4; ++mi)
#pragma unroll
            for (int r = 0; r < 4; ++r) {
                const int e = m0 + wm * 64 + mi * 16 + quad * 4 + r;      // 0..511
                const float bias_e = h2f(bias[e]);
#pragma unroll
                for (int ni = 0; ni < 4; ++ni) {
                    const int tok = n0 + wn * 64 + ni * 16 + lane15;
                    const int b = tok >> 11, kk = tok & 2047;
                    vt[(size_t)b * 1048576 + tidx(e, kk, 64)] =
                        f2h_bits(acc[mi][ni][r] + bias_e);
                }
            }
    }
}

// ---------------- gemmS: gemm + bitmask epilogue (permuted bit order) -------
__global__ __launch_bounds__(256) void gemmS(
    const u16* __restrict__ qb, const u16* __restrict__ kb,
    const u64* __restrict__ mbits, u16* __restrict__ Sdst, int b0)
{
    GEMM_PRE();
    const int zb = blockIdx.z;
    const int b = b0 + zb;
    const int hh = blockIdx.y * 16 + blockIdx.x;
    const int sl = (hh & 7) * 32 + (hh >> 3);
    const int m0 = (sl >> 4) * 128, n0 = (sl & 15) * 128;

    const u16* A = qb + (size_t)((b * S_DIM + m0) >> 7) * 16 * 4096;
    const u16* B = kb + (size_t)((b * S_DIM + n0) >> 7) * 16 * 4096;
    gemm_core<0, 0, 0>(A, 512, B, 512, 512, As, Bs, acc, accS);

    // bit word for this wave's 64-col window; permuted bit p = p0 + 4*ni
    const u64* mb = mbits + (size_t)b * S_DIM * 32 + (n0 >> 6) + wn;
    const int p0 = (lane15 & 3) * 16 + (lane15 >> 2);
    u16* Sb = Sdst + (size_t)zb * 4194304;      // tiled [16 RB][64 T][512]g
#pragma unroll
    for (int mi = 0; mi < 4; ++mi)
#pragma unroll
        for (int r = 0; r < 4; ++r) {
            const int row = m0 + wm * 64 + mi * 16 + quad * 4 + r;
            const u64 wbits = mb[(size_t)row * 32];
            const int col0 = n0 + wn * 64 + lane15;
#pragma unroll
            for (int ni = 0; ni < 4; ++ni) {
                const int masked = (int)((wbits >> (p0 + 4 * ni)) & 1);
                const float p = masked ? 0.f : __expf(acc[mi][ni][r] * SCALE);
                Sb[tidx(row, col0 + ni * 16, 64)] = f2h_bits(p);
            }
        }
}

// ---------------- gemmO: R15 verbatim ----------------
__global__ __launch_bounds__(256) void gemmO(
    const u16* __restrict__ Ssrc, const u16* __restrict__ vt,
    float* __restrict__ outp, int b0)
{
    GEMM_PRE();
    const int zb = blockIdx.z;
    const int b = b0 + zb;
    const int hh = blockIdx.y * 4 + blockIdx.x;
    const int sl = (hh & 7) * 8 + (hh >> 3);
    const int m0 = (sl >> 2) * 128, n0 = (sl & 3) * 128;
    const u16* A = Ssrc + (size_t)zb * 4194304 + (size_t)(m0 >> 7) * 64 * 4096;
    const u16* B = vt + (size_t)b * 1048576 + (size_t)(n0 >> 7) * 64 * 4096;

    gemm_core<1, 0, 0>(A, S_DIM, B, S_DIM, S_DIM, As, Bs, acc, accS);

#pragma unroll
    for (int mi = 0; mi < 4; ++mi)
#pragma unroll
        for (int r = 0; r < 4; ++r) {
            const int row = m0 + wm * 64 + mi * 16 + quad * 4 + r;
            const float inv = 1.f / accS[mi][r];
#pragma unroll
            for (int ni = 0; ni < 4; ++ni) {
                const int col = n0 + wn * 64 + ni * 16 + lane15;
                outp[((size_t)b * S_DIM + row) * E_DIM + col] = acc[mi][ni][r] * inv;
            }
        }
}

extern "C" void kernel_launch(void* const* d_in, const int* in_sizes, int n_in,
                              void* d_out, int out_size, void* d_ws, size_t ws_size,
                              hipStream_t stream) {
    const void* x    = d_in[0];
    const int*  mask = (const int*)d_in[1];
    const void* wq   = d_in[2];
    const void* bq   = d_in[3];
    const void* wk   = d_in[4];
    const void* bk   = d_in[5];
    const void* wv   = d_in[6];
    const void* bv   = d_in[7];

    const size_t MB    = 1ull << 20;
    const size_t QSZ   = (size_t)NROWS * E_DIM;         // u16 elems per Q/K/Vt/xh
    const size_t S_PB  = (size_t)S_DIM * S_DIM;         // u16 elems per S batch
    const size_t MBITS = NWORDS * 8;                    // 4 MB

    u16* wb   = (u16*)d_ws;                             // 2 MB (weights+bias f16)
    u16* qb   = (u16*)((char*)d_ws + 2 * MB);
    u16* kb   = qb + QSZ;
    u16* vtb  = kb + QSZ;
    u64* mbit = (u64*)(vtb + QSZ);                      // 4 MB bitmask
    u16* xh   = (u16*)((char*)mbit + MBITS);            // 16.8 MB f16 x (dead after proj)
    u16* sS   = xh;                                     // S scratch aliases xh

    const size_t fixed = 2 * MB + 3 * QSZ * 2 + MBITS;  // 56.4 MB (pre-xh)
    const size_t avail = (ws_size > fixed) ? (ws_size - fixed) : 0;
    const int use_xh = avail >= (QSZ * 2 + 2 * S_PB);   // xh + >=2 S batches
    const size_t availB = avail / (S_PB * 2);
    const int P = (availB >= 8) ? 8 : (availB >= 4) ? 4 : (availB >= 2) ? 2 : 1;

    conv_w<<<dim3(128, 3), 256, 0, stream>>>(wq, wk, wv, bq, bk, bv, wb);
    conv_mask<<<4096, 256, 0, stream>>>(mask, mbit);

    if (use_xh) {
        conv_x<<<NROWS / 4, 256, 0, stream>>>(x, wq, xh);
        proj_gemm<0><<<dim3(4, 128, 3), 256, 0, stream>>>(xh, wb, qb, kb, vtb);
    } else {
        if (in_sizes[0] >= (int)(NROWS * 512 * 4))
            proj_gemm<1><<<dim3(4, 128, 3), 256, 0, stream>>>(x, wb, qb, kb, vtb);
        else
            proj_gemm<2><<<dim3(4, 128, 3), 256, 0, stream>>>(x, wb, qb, kb, vtb);
    }

    for (int p = 0; p < 8; p += P) {
        gemmS<<<dim3(16, 16, P), 256, 0, stream>>>(qb, kb, mbit, sS, p);
        gemmO<<<dim3(4, 16, P), 256, 0, stream>>>(sS, vtb, (float*)d_out, p);
    }
}